// Round 3
// baseline (811.269 us; speedup 1.0000x reference)
//
#include <hip/hip_runtime.h>
#include <hip/hip_bf16.h>

#define FEAT 128
#define NRELS 8
#define KTOT 1024          // NRELS * FEAT
#define BN 32              // dst nodes per aggemm block

typedef __bf16 bf16_t;
typedef __bf16 bf16x8_t __attribute__((ext_vector_type(8)));
typedef float f32x4 __attribute__((ext_vector_type(4)));

struct __align__(8) PackedEdge { int row; float scale; };  // row=(src<<8)|(local<<3)|rel

static inline size_t align256(size_t x) { return (x + 255) & ~(size_t)255; }

// ---------------------------------------------------------------------------
// w [R][d][f] fp32 -> wt2 [f][r*128+d] bf16 : GEMM B-operand, k contiguous per
// f row. 256 KiB total, L2-resident during GEMM.
__global__ void k_convert_w2(const float* __restrict__ w, bf16_t* __restrict__ wt2) {
    int i = blockIdx.x * blockDim.x + threadIdx.x;
    if (i >= NRELS * FEAT * FEAT) return;
    int r = i >> 14;
    int rem = i & 16383;
    int d = rem >> 7;
    int f = rem & 127;
    wt2[(size_t)f * KTOT + r * FEAT + d] = (bf16_t)w[i];
}

// ---------------------------------------------------------------------------
// Gate: sg[n][r] = sigmoid(sum_d h[n][d]*gw[r][d]); fp32. One wave per node.
__global__ void k_gate(const float* __restrict__ h, const float* __restrict__ gw,
                       float* __restrict__ sg, int ncount) {
    int wv = (int)((blockIdx.x * blockDim.x + threadIdx.x) >> 6);
    int lane = threadIdx.x & 63;
    if (wv >= ncount) return;
    float2 hv = *reinterpret_cast<const float2*>(h + (size_t)wv * FEAT + lane * 2);
    float res[NRELS];
#pragma unroll
    for (int r = 0; r < NRELS; ++r) {
        float2 wvv = *reinterpret_cast<const float2*>(gw + r * FEAT + lane * 2);
        float s = hv.x * wvv.x + hv.y * wvv.y;
#pragma unroll
        for (int off = 32; off; off >>= 1) s += __shfl_xor(s, off, 64);
        res[r] = s;
    }
    if (lane == 0) {
#pragma unroll
        for (int r = 0; r < NRELS; ++r)
            sg[(size_t)wv * NRELS + r] = 1.0f / (1.0f + __expf(-res[r]));
    }
}

// ---------------------------------------------------------------------------
// Per-32-node-block edge counts (only block-level CSR needed now).
__global__ void k_degree_blk(const int* __restrict__ dstv, int* __restrict__ degb,
                             int nedges) {
    int e = blockIdx.x * blockDim.x + threadIdx.x;
    if (e >= nedges) return;
    atomicAdd(&degb[dstv[e] >> 5], 1);   // BN = 32
}

// Single-block exclusive scan over nbk (<1e4) block counts; base[nbk] = total.
__global__ __launch_bounds__(1024) void k_scan_one(const int* __restrict__ deg,
                                                   int* __restrict__ base, int nb) {
    __shared__ int sm[1024];
    __shared__ int carry;
    int t = threadIdx.x;
    if (t == 0) carry = 0;
    __syncthreads();
    for (int s0 = 0; s0 < nb; s0 += 1024) {
        int v = (s0 + t < nb) ? deg[s0 + t] : 0;
        sm[t] = v;
        __syncthreads();
        for (int off = 1; off < 1024; off <<= 1) {
            int x = (t >= off) ? sm[t - off] : 0;
            __syncthreads();
            sm[t] += x;
            __syncthreads();
        }
        if (s0 + t < nb) base[s0 + t] = carry + sm[t] - v;
        int tot = sm[1023];
        __syncthreads();
        if (t == 0) carry += tot;
        __syncthreads();
    }
    if (t == 0) base[nb] = carry;
}

// Fill packed records {(src<<8)|(dst&31)<<3|rel, norm*sig} into block buckets.
__global__ void k_fill(const int* __restrict__ src, const int* __restrict__ dstv,
                       const int* __restrict__ rel, const float* __restrict__ nrm,
                       const float* __restrict__ sg, const int* __restrict__ bbase,
                       int* __restrict__ cursor, PackedEdge* __restrict__ packed,
                       int nedges) {
    int e = blockIdx.x * blockDim.x + threadIdx.x;
    if (e >= nedges) return;
    int d = dstv[e];
    int s = src[e];
    int r = rel[e];
    int bk = d >> 5;
    int pos = bbase[bk] + atomicAdd(&cursor[bk], 1);
    PackedEdge p;
    p.row = (s << 8) | ((d & 31) << 3) | r;
    p.scale = nrm[e] * sg[(size_t)s * NRELS + r];
    packed[pos] = p;
}

// ---------------------------------------------------------------------------
// Fused aggregate + GEMM + relu. Block = 1024 threads (16 waves), 32 dst nodes.
// LDS: agg fp32 [32][1024] = 128 KiB (XOR-swizzled at 16B chunks, chunk^(node&7));
// partial-C / final-C buffers alias agg after the GEMM reads complete.
//
// Phase A (edge-parallel): 64 groups of 16 lanes; each group owns one edge per
//   iteration: reads the src h row fp32 (2x float4/lane, coalesced 256B), scales
//   by the packed fp32 weight, ds_add_f32 into agg[local][r*128+f]. Atomics make
//   edge order irrelevant -> no rel sorting, exact fp32 accumulation.
// Phase B: M=32(nodes) x N=128(f) x K=1024 GEMM, 16 waves = 4 f-slices x 4
//   K-quarters (split-K). A-frags: 2x ds_read_b128 fp32 + cvt->bf16 (swizzled,
//   uniform-bank); B-frags: bf16x8 from wt2 (each 16B read exactly once/block).
//   Split-K partials reduced via aliased LDS, relu, then fully-coalesced
//   float4 stores through a [32][128] staging tile.
__global__ __launch_bounds__(1024, 4) void k_aggemm(const float* __restrict__ h,
                                                    const bf16_t* __restrict__ wt2,
                                                    const PackedEdge* __restrict__ packed,
                                                    const int* __restrict__ bbase,
                                                    float* __restrict__ out, int nnodes) {
    __shared__ __align__(16) float lds[BN * KTOT];   // 128 KiB
    const int t = threadIdx.x;
    const int nb0 = blockIdx.x * BN;

    // zero agg tile: 32768 floats / 1024 threads = 8 x f32x4 each
    {
        f32x4 z = {0.f, 0.f, 0.f, 0.f};
#pragma unroll
        for (int i = 0; i < 8; ++i)
            reinterpret_cast<f32x4*>(lds)[t + i * 1024] = z;
    }
    __syncthreads();

    // ---------------- Phase A: edge-parallel aggregation ----------------
    {
        const int grp = t >> 4;          // 0..63 edge slots
        const int l16 = t & 15;          // feature chunk within row
        const int ebeg = bbase[blockIdx.x];
        const int eend = bbase[blockIdx.x + 1];
        int j = ebeg + grp;
        PackedEdge p = {0, 0.f};
        if (j < eend) p = packed[j];
#pragma unroll 1
        for (; j < eend; j += 64) {
            PackedEdge pn = p;
            if (j + 64 < eend) pn = packed[j + 64];   // prefetch next record
            const int srow = p.row >> 8;
            const int local = (p.row >> 3) & 31;
            const int r = p.row & 7;
            const float4* hp = reinterpret_cast<const float4*>(h + (size_t)srow * FEAT);
            float4 v0 = hp[l16];
            float4 v1 = hp[l16 + 16];
            const float s = p.scale;
            float* rowp = lds + local * KTOT;
            const int sw = local & 7;
            const int c0 = ((r * 32 + l16) ^ sw) * 4;        // swizzled float idx
            const int c1 = ((r * 32 + 16 + l16) ^ sw) * 4;
            atomicAdd(rowp + c0 + 0, v0.x * s);
            atomicAdd(rowp + c0 + 1, v0.y * s);
            atomicAdd(rowp + c0 + 2, v0.z * s);
            atomicAdd(rowp + c0 + 3, v0.w * s);
            atomicAdd(rowp + c1 + 0, v1.x * s);
            atomicAdd(rowp + c1 + 1, v1.y * s);
            atomicAdd(rowp + c1 + 2, v1.z * s);
            atomicAdd(rowp + c1 + 3, v1.w * s);
            p = pn;
        }
    }
    __syncthreads();

    // ---------------- Phase B: split-K GEMM ----------------
    const int lane = t & 63;
    const int wv = t >> 6;               // 0..15
    const int l15 = lane & 15;
    const int lhi = lane >> 4;
    const int fs = wv & 3;               // f-slice (32 feats)
    const int kh = wv >> 2;              // K-quarter (256 k)

    f32x4 acc[2][2];
#pragma unroll
    for (int a = 0; a < 2; ++a)
#pragma unroll
        for (int b = 0; b < 2; ++b) acc[a][b] = (f32x4){0.f, 0.f, 0.f, 0.f};

    const bf16_t* bp0 = wt2 + (size_t)(fs * 32 + l15) * KTOT + kh * 256 + lhi * 8;
    const bf16_t* bp1 = bp0 + (size_t)16 * KTOT;
    const int swb = l15 & 7;

#pragma unroll
    for (int ks = 0; ks < 8; ++ks) {
        const int cb = kh * 64 + ks * 8 + lhi * 2;   // 16B chunk index of k-octet
        bf16x8_t afr[2];
#pragma unroll
        for (int tm = 0; tm < 2; ++tm) {
            const f32x4* ap = reinterpret_cast<const f32x4*>(lds + (tm * 16 + l15) * KTOT);
            f32x4 lo = ap[cb ^ swb];
            f32x4 hi = ap[(cb + 1) ^ swb];
            bf16x8_t o;
            o[0] = (bf16_t)lo[0]; o[1] = (bf16_t)lo[1];
            o[2] = (bf16_t)lo[2]; o[3] = (bf16_t)lo[3];
            o[4] = (bf16_t)hi[0]; o[5] = (bf16_t)hi[1];
            o[6] = (bf16_t)hi[2]; o[7] = (bf16_t)hi[3];
            afr[tm] = o;
        }
        bf16x8_t b0 = *reinterpret_cast<const bf16x8_t*>(bp0 + ks * 32);
        bf16x8_t b1 = *reinterpret_cast<const bf16x8_t*>(bp1 + ks * 32);
        acc[0][0] = __builtin_amdgcn_mfma_f32_16x16x32_bf16(afr[0], b0, acc[0][0], 0, 0, 0);
        acc[1][0] = __builtin_amdgcn_mfma_f32_16x16x32_bf16(afr[1], b0, acc[1][0], 0, 0, 0);
        acc[0][1] = __builtin_amdgcn_mfma_f32_16x16x32_bf16(afr[0], b1, acc[0][1], 0, 0, 0);
        acc[1][1] = __builtin_amdgcn_mfma_f32_16x16x32_bf16(afr[1], b1, acc[1][1], 0, 0, 0);
    }
    __syncthreads();   // all agg reads done; LDS reusable

    // split-K partials: kh>0 waves park C in aliased LDS
    if (kh > 0) {
        float* buf = lds + ((kh - 1) * 4 + fs) * 1024;
#pragma unroll
        for (int tm = 0; tm < 2; ++tm)
#pragma unroll
            for (int tn = 0; tn < 2; ++tn)
#pragma unroll
                for (int i = 0; i < 4; ++i)
                    buf[(tm * 16 + lhi * 4 + i) * 32 + tn * 16 + l15] = acc[tm][tn][i];
    }
    __syncthreads();
    if (kh == 0) {
#pragma unroll
        for (int kk = 0; kk < 3; ++kk) {
            const float* buf = lds + (kk * 4 + fs) * 1024;
#pragma unroll
            for (int tm = 0; tm < 2; ++tm)
#pragma unroll
                for (int tn = 0; tn < 2; ++tn)
#pragma unroll
                    for (int i = 0; i < 4; ++i)
                        acc[tm][tn][i] += buf[(tm * 16 + lhi * 4 + i) * 32 + tn * 16 + l15];
        }
        // relu + stage final C [32][128] for coalesced stores
        float* fb = lds + 16 * 1024;
#pragma unroll
        for (int tm = 0; tm < 2; ++tm)
#pragma unroll
            for (int tn = 0; tn < 2; ++tn)
#pragma unroll
                for (int i = 0; i < 4; ++i)
                    fb[(tm * 16 + lhi * 4 + i) * FEAT + fs * 32 + tn * 16 + l15] =
                        fmaxf(acc[tm][tn][i], 0.f);
    }
    __syncthreads();

    // coalesced store: thread t -> node t>>5, feats (t&31)*4..+4
    {
        const int node = t >> 5;
        const int fi = t & 31;
        const int gnode = nb0 + node;
        if (gnode < nnodes) {
            f32x4 v = *reinterpret_cast<const f32x4*>(lds + 16 * 1024 + node * FEAT + fi * 4);
            *reinterpret_cast<f32x4*>(out + (size_t)gnode * FEAT + fi * 4) = v;
        }
    }
}

// ---------------------------------------------------------------------------
extern "C" void kernel_launch(void* const* d_in, const int* in_sizes, int n_in,
                              void* d_out, int out_size, void* d_ws, size_t ws_size,
                              hipStream_t stream) {
    const float* h = (const float*)d_in[0];
    const float* w = (const float*)d_in[1];
    const float* gw = (const float*)d_in[2];
    const float* nrm = (const float*)d_in[3];
    const int* src = (const int*)d_in[4];
    const int* dst = (const int*)d_in[5];
    const int* rel = (const int*)d_in[6];
    float* out = (float*)d_out;

    const int N = in_sizes[0] / FEAT;
    const int E = in_sizes[4];
    const int nbk = (N + BN - 1) / BN;

    char* ws = (char*)d_ws;
    const size_t wt2B = align256((size_t)FEAT * KTOT * sizeof(bf16_t));   // 256 KiB
    const size_t sgB  = align256((size_t)N * NRELS * sizeof(float));      // 3.2 MB
    const size_t ctrB = align256((size_t)(2 * nbk) * sizeof(int));        // degb+cursor
    const size_t bbB  = align256((size_t)(nbk + 1) * sizeof(int));

    bf16_t* wt2 = (bf16_t*)ws;
    float* sg = (float*)(ws + wt2B);
    int* degb = (int*)(ws + wt2B + sgB);              // [nbk] counts
    int* cursor = degb + nbk;                         // [nbk] fill cursors
    int* bbase = (int*)(ws + wt2B + sgB + ctrB);      // [nbk+1] block offsets
    PackedEdge* packed = (PackedEdge*)(ws + wt2B + sgB + ctrB + bbB);

    hipMemsetAsync(degb, 0, (size_t)(2 * nbk) * sizeof(int), stream);
    k_convert_w2<<<(NRELS * FEAT * FEAT + 255) / 256, 256, 0, stream>>>(w, wt2);
    k_gate<<<(N + 3) / 4, 256, 0, stream>>>(h, gw, sg, N);
    k_degree_blk<<<(E + 255) / 256, 256, 0, stream>>>(dst, degb, E);
    k_scan_one<<<1, 1024, 0, stream>>>(degb, bbase, nbk);
    k_fill<<<(E + 255) / 256, 256, 0, stream>>>(src, dst, rel, nrm, sg, bbase,
                                                cursor, packed, E);
    k_aggemm<<<nbk, 1024, 0, stream>>>(h, wt2, packed, bbase, out, N);
}

// Round 4
// 523.657 us; speedup vs baseline: 1.5492x; 1.5492x over previous
//
#include <hip/hip_runtime.h>
#include <hip/hip_bf16.h>

#define FEAT 128
#define NRELS 8
#define SCAN_CHUNK 256
#define GT 64   // GEMM node tile

typedef __bf16 bf16_t;
typedef __bf16 bf16x2_t __attribute__((ext_vector_type(2)));
typedef __bf16 bf16x4_t __attribute__((ext_vector_type(4)));
typedef __bf16 bf16x8_t __attribute__((ext_vector_type(8)));
typedef float f32x4 __attribute__((ext_vector_type(4)));

struct __align__(8) PackedEdge { int row; float scale; };

static inline size_t align256(size_t x) { return (x + 255) & ~(size_t)255; }

// ---------------------------------------------------------------------------
// Weight [R][d][f] fp32 -> Wt [R][f][d] bf16 (transposed: MFMA A-fragments need
// contiguous k=d per lane -> 16B vector loads).
__global__ void k_convert_w(const float* __restrict__ w, bf16_t* __restrict__ wt) {
    int i = blockIdx.x * blockDim.x + threadIdx.x;
    if (i >= NRELS * FEAT * FEAT) return;
    int r = i >> 14;
    int rem = i & 16383;
    int d = rem >> 7;
    int f = rem & 127;
    wt[(r << 14) + (f << 7) + d] = (bf16_t)w[i];
}

// ---------------------------------------------------------------------------
// Gate: sg[n][r] = sigmoid(sum_d h[n][d]*gw[r][d]); fp32. One wave per node.
// Lane partition: lane = r*8 + g; each lane dots 16 d's (4 x float4) of rel r;
// 3-step shfl_xor reduce within the 8-lane g-group (vs 48-deep chain before).
__global__ __launch_bounds__(256) void k_gate(const float* __restrict__ h,
                                              const float* __restrict__ gw,
                                              float* __restrict__ sg,
                                              int node0, int ncount) {
    int wv = (int)((blockIdx.x * blockDim.x + threadIdx.x) >> 6);
    int lane = threadIdx.x & 63;
    if (wv >= ncount) return;
    int r = lane >> 3;          // relation 0..7
    int g = lane & 7;           // d-group: d in [g*16, g*16+16)
    const float4* hp = reinterpret_cast<const float4*>(
        h + (size_t)(node0 + wv) * FEAT + g * 16);
    const float4* wp = reinterpret_cast<const float4*>(gw + r * FEAT + g * 16);
    float s = 0.f;
#pragma unroll
    for (int i = 0; i < 4; ++i) {
        float4 a = hp[i];
        float4 b = wp[i];
        s += a.x * b.x + a.y * b.y + a.z * b.z + a.w * b.w;
    }
    s += __shfl_xor(s, 1, 64);
    s += __shfl_xor(s, 2, 64);
    s += __shfl_xor(s, 4, 64);
    if (g == 0) sg[(size_t)wv * NRELS + r] = 1.0f / (1.0f + __expf(-s));
}

// ---------------------------------------------------------------------------
// GEMM, all 8 relations per block. Block = 4 waves = one 64-node tile.
// Reads h fp32 directly (in-register bf16 convert; no hb pass). Gate sigmoid
// folded into the stored hall values. hall layout [R][Nceil][F]: per relation
// the block's 64x128 tile is a CONTIGUOUS 16KB region -> after an LDS
// transpose each wave stores 64 lanes x 16B = contiguous 1KB.
// LDS is XOR-swizzled at 16B-chunk granularity (chunk ^ (node&15)) so both the
// acc-layout writes and the row-major reads stay ~conflict-free.
// __launch_bounds__(256,5): 5 blocks/CU (LDS 32KB, VGPR<=102) -- round-1's
// (256,2) strangled occupancy to 25% and left the kernel latency-bound.
__global__ __launch_bounds__(256, 5) void k_gemm8(const float* __restrict__ h,
                                                  const bf16_t* __restrict__ wt,
                                                  const float* __restrict__ sg,
                                                  bf16_t* __restrict__ hall,
                                                  int nvalid, int planeElems) {
    __shared__ __align__(16) bf16_t lds[2][GT * FEAT];
    const int tile = blockIdx.x;
    const int t = threadIdx.x;
    const int wv = t >> 6;
    const int lane = t & 63;
    const int l15 = lane & 15;
    const int lhi = lane >> 4;
    const int f_base = wv * 32;        // wave covers f in [f_base, f_base+32)
    const int node_base = tile * GT;

    // B-fragments: B[k][n], n = tn*16 + l15, k = ks*32 + lhi*8 + j
    bf16x8_t bfrag[4][4];
#pragma unroll
    for (int tn = 0; tn < 4; ++tn) {
        int node = node_base + tn * 16 + l15;
        const float* hp = h + (size_t)node * FEAT + lhi * 8;
        bool valid = node < nvalid;
#pragma unroll
        for (int ks = 0; ks < 4; ++ks) {
            bf16x8_t o;
            if (valid) {
                float4 v0 = reinterpret_cast<const float4*>(hp + ks * 32)[0];
                float4 v1 = reinterpret_cast<const float4*>(hp + ks * 32)[1];
                o[0] = (bf16_t)v0.x; o[1] = (bf16_t)v0.y;
                o[2] = (bf16_t)v0.z; o[3] = (bf16_t)v0.w;
                o[4] = (bf16_t)v1.x; o[5] = (bf16_t)v1.y;
                o[6] = (bf16_t)v1.z; o[7] = (bf16_t)v1.w;
            } else {
#pragma unroll
                for (int i = 0; i < 8; ++i) o[i] = (bf16_t)0.f;
            }
            bfrag[tn][ks] = o;
        }
    }

#pragma unroll 1
    for (int r = 0; r < NRELS; ++r) {
        // A-fragments from Wt[r]: A[m=f][k], k contiguous per lane (L2-hot)
        bf16x8_t afrag[2][4];
#pragma unroll
        for (int tm = 0; tm < 2; ++tm) {
            const bf16_t* ap = wt + ((size_t)r << 14) +
                               (size_t)(f_base + tm * 16 + l15) * FEAT + lhi * 8;
#pragma unroll
            for (int ks = 0; ks < 4; ++ks)
                afrag[tm][ks] = *reinterpret_cast<const bf16x8_t*>(ap + ks * 32);
        }
        // Gate values for this wave's node columns (L2-resident sg)
        float g[4];
#pragma unroll
        for (int tn = 0; tn < 4; ++tn) {
            int node = node_base + tn * 16 + l15;
            g[tn] = (node < nvalid) ? sg[(size_t)node * NRELS + r] : 0.f;
        }

        f32x4 acc[2][4];
#pragma unroll
        for (int tm = 0; tm < 2; ++tm)
#pragma unroll
            for (int tn = 0; tn < 4; ++tn)
                acc[tm][tn] = (f32x4){0.f, 0.f, 0.f, 0.f};

#pragma unroll
        for (int ks = 0; ks < 4; ++ks)
#pragma unroll
            for (int tn = 0; tn < 4; ++tn)
#pragma unroll
                for (int tm = 0; tm < 2; ++tm)
                    acc[tm][tn] = __builtin_amdgcn_mfma_f32_16x16x32_bf16(
                        afrag[tm][ks], bfrag[tn][ks], acc[tm][tn], 0, 0, 0);

        // Scale by gate, convert, stage into LDS (swizzled).
        // C layout: col(l15)=node, row(lhi*4+i)=f  (m89-verified)
        bf16_t* buf = lds[r & 1];
#pragma unroll
        for (int tm = 0; tm < 2; ++tm) {
            int f0 = f_base + tm * 16 + lhi * 4;
#pragma unroll
            for (int tn = 0; tn < 4; ++tn) {
                int node = tn * 16 + l15;
                bf16x4_t o;
                o.x = (bf16_t)(acc[tm][tn][0] * g[tn]);
                o.y = (bf16_t)(acc[tm][tn][1] * g[tn]);
                o.z = (bf16_t)(acc[tm][tn][2] * g[tn]);
                o.w = (bf16_t)(acc[tm][tn][3] * g[tn]);
                int idx = node * FEAT + ((((f0 >> 3) ^ node) & 15) << 3) + (f0 & 7);
                *reinterpret_cast<bf16x4_t*>(&buf[idx]) = o;
            }
        }
        __syncthreads();   // single barrier per r; LDS double-buffer covers WAR

        // Coalesced store: per wave, 4 consecutive node rows x 16 chunks = 1KB
        bf16_t* plane = hall + (size_t)r * planeElems;
#pragma unroll
        for (int it = 0; it < 4; ++it) {
            int node = it * 16 + (t >> 4);
            int sub = t & 15;
            bf16x8_t v = *reinterpret_cast<const bf16x8_t*>(
                &buf[node * FEAT + (((sub ^ node) & 15) << 3)]);
            *reinterpret_cast<bf16x8_t*>(
                plane + (size_t)(node_base + node) * FEAT + sub * 8) = v;
        }
    }
}

// ---------------------------------------------------------------------------
// CSR build
__global__ void k_degree(const int* __restrict__ dstv, int* __restrict__ deg, int nedges) {
    int e = blockIdx.x * blockDim.x + threadIdx.x;
    if (e >= nedges) return;
    atomicAdd(&deg[dstv[e]], 1);
}

__global__ __launch_bounds__(256) void k_scan_block(const int* __restrict__ in,
                                                    int* __restrict__ outv,
                                                    int* __restrict__ bsum, int n) {
    __shared__ int sm[256];
    int t = threadIdx.x;
    int idx = blockIdx.x * SCAN_CHUNK + t;
    int v = (idx < n) ? in[idx] : 0;
    sm[t] = v;
    __syncthreads();
    for (int off = 1; off < 256; off <<= 1) {
        int x = (t >= off) ? sm[t - off] : 0;
        __syncthreads();
        sm[t] += x;
        __syncthreads();
    }
    if (idx < n) outv[idx] = sm[t] - v;
    if (t == 255) bsum[blockIdx.x] = sm[255];
}

__global__ __launch_bounds__(1024) void k_scan_tops(int* __restrict__ bsum, int nb,
                                                    int* __restrict__ rowptr_end) {
    __shared__ int sm[1024];
    int t = threadIdx.x;
    if (nb <= 1024) {
        int v = (t < nb) ? bsum[t] : 0;
        sm[t] = v;
        __syncthreads();
        for (int off = 1; off < 1024; off <<= 1) {
            int x = (t >= off) ? sm[t - off] : 0;
            __syncthreads();
            sm[t] += x;
            __syncthreads();
        }
        if (t < nb) bsum[t] = sm[t] - v;
        if (t == 1023) *rowptr_end = sm[1023];
    } else if (t == 0) {
        int run = 0;
        for (int b = 0; b < nb; ++b) { int v = bsum[b]; bsum[b] = run; run += v; }
        *rowptr_end = run;
    }
}

__global__ void k_scan_add(int* __restrict__ rowptr, const int* __restrict__ bsum, int n) {
    int i = blockIdx.x * blockDim.x + threadIdx.x;
    if (i >= n) return;
    rowptr[i] += bsum[i >> 8];   // 256 = 1<<8
}

// Fill packed edge records {hall_row, norm} at CSR slots. Gate is already
// folded into hall, so scale = norm only (no random sg read).
__global__ void k_fill(const int* __restrict__ src, const int* __restrict__ dstv,
                       const int* __restrict__ rel, const float* __restrict__ nrm,
                       const int* __restrict__ rowptr, int* __restrict__ cursor,
                       PackedEdge* __restrict__ packed, int planeRows, int nedges) {
    int e = blockIdx.x * blockDim.x + threadIdx.x;
    if (e >= nedges) return;
    int d = dstv[e];
    int pos = rowptr[d] + atomicAdd(&cursor[d], 1);
    PackedEdge p;
    p.row = rel[e] * planeRows + src[e];
    p.scale = nrm[e];
    packed[pos] = p;
}

// ---------------------------------------------------------------------------
// Gather: one wave per dst node, 4 edges per iteration (16 lanes each:
// 16 lanes x bf16x8 = one 256B hall row). Reduce via shfl_xor(16) + (32).
__global__ __launch_bounds__(256) void k_gather(const bf16_t* __restrict__ hall,
                                                const PackedEdge* __restrict__ packed,
                                                const int* __restrict__ rowptr,
                                                float* __restrict__ out, int nnodes) {
    int wv = (int)((blockIdx.x * blockDim.x + threadIdx.x) >> 6);
    int lane = threadIdx.x & 63;
    if (wv >= nnodes) return;
    int q = lane >> 4;           // edge slot 0..3
    int sub = lane & 15;         // feature group: feats [sub*8, sub*8+8)
    int beg = rowptr[wv];
    int end = rowptr[wv + 1];
    float a[8];
#pragma unroll
    for (int i = 0; i < 8; ++i) a[i] = 0.f;
    int j = beg + q;
    PackedEdge p;
    if (j < end) p = packed[j];
#pragma unroll 1
    for (; j < end; j += 4) {
        PackedEdge pn;
        if (j + 4 < end) pn = packed[j + 4];     // prefetch next record
        bf16x8_t mv = *reinterpret_cast<const bf16x8_t*>(
            hall + (size_t)p.row * FEAT + sub * 8);
        float s = p.scale;
        a[0] += (float)mv[0] * s;
        a[1] += (float)mv[1] * s;
        a[2] += (float)mv[2] * s;
        a[3] += (float)mv[3] * s;
        a[4] += (float)mv[4] * s;
        a[5] += (float)mv[5] * s;
        a[6] += (float)mv[6] * s;
        a[7] += (float)mv[7] * s;
        p = pn;
    }
#pragma unroll
    for (int i = 0; i < 8; ++i) {
        a[i] += __shfl_xor(a[i], 16);
        a[i] += __shfl_xor(a[i], 32);
    }
    if (q == 0) {
        float4 o0, o1;
        o0.x = fmaxf(a[0], 0.f); o0.y = fmaxf(a[1], 0.f);
        o0.z = fmaxf(a[2], 0.f); o0.w = fmaxf(a[3], 0.f);
        o1.x = fmaxf(a[4], 0.f); o1.y = fmaxf(a[5], 0.f);
        o1.z = fmaxf(a[6], 0.f); o1.w = fmaxf(a[7], 0.f);
        float4* op = reinterpret_cast<float4*>(out + (size_t)wv * FEAT + sub * 8);
        op[0] = o0;
        op[1] = o1;
    }
}

// ---------------------------------------------------------------------------
// Fallback path (small ws): chunked atomic scatter. hall layout [R][Cc][F].
__global__ __launch_bounds__(256) void k_scatter(const bf16_t* __restrict__ hall,
                                                 const float* __restrict__ nrm,
                                                 const int* __restrict__ src,
                                                 const int* __restrict__ dstv,
                                                 const int* __restrict__ rel,
                                                 float* __restrict__ out,
                                                 int node0, int ncount, int planeRows,
                                                 int nedges) {
    int e = (int)((blockIdx.x * blockDim.x + threadIdx.x) >> 6);
    if (e >= nedges) return;
    int lane = threadIdx.x & 63;
    int s = src[e] - node0;
    if ((unsigned)s >= (unsigned)ncount) return;
    int r = rel[e];
    float scale = nrm[e];
    bf16x2_t mv = *reinterpret_cast<const bf16x2_t*>(
        hall + (size_t)(r * planeRows + s) * FEAT + lane * 2);
    float* op = out + (size_t)dstv[e] * FEAT + lane * 2;
    unsafeAtomicAdd(op, (float)mv.x * scale);
    unsafeAtomicAdd(op + 1, (float)mv.y * scale);
}

__global__ void k_relu(float4* __restrict__ out, int total4) {
    int i = blockIdx.x * blockDim.x + threadIdx.x;
    if (i >= total4) return;
    float4 v = out[i];
    v.x = fmaxf(v.x, 0.f);
    v.y = fmaxf(v.y, 0.f);
    v.z = fmaxf(v.z, 0.f);
    v.w = fmaxf(v.w, 0.f);
    out[i] = v;
}

// ---------------------------------------------------------------------------
extern "C" void kernel_launch(void* const* d_in, const int* in_sizes, int n_in,
                              void* d_out, int out_size, void* d_ws, size_t ws_size,
                              hipStream_t stream) {
    const float* h = (const float*)d_in[0];
    const float* w = (const float*)d_in[1];
    const float* gw = (const float*)d_in[2];
    const float* nrm = (const float*)d_in[3];
    const int* src = (const int*)d_in[4];
    const int* dst = (const int*)d_in[5];
    const int* rel = (const int*)d_in[6];
    float* out = (float*)d_out;

    const int N = in_sizes[0] / FEAT;
    const int E = in_sizes[4];
    const int Nceil = ((N + GT - 1) / GT) * GT;
    const int nb = (N + SCAN_CHUNK - 1) / SCAN_CHUNK;

    char* ws = (char*)d_ws;
    const size_t wtB = (size_t)NRELS * FEAT * FEAT * sizeof(bf16_t);      // 256 KiB
    const size_t hallB = (size_t)NRELS * Nceil * FEAT * sizeof(bf16_t);   // ~205 MB
    const size_t sgB = align256((size_t)N * NRELS * sizeof(float));
    const size_t degB = align256((size_t)N * sizeof(int));
    const size_t rowB = align256((size_t)(N + 1) * sizeof(int));
    const size_t bsB = align256((size_t)nb * sizeof(int));
    const size_t pkB = align256((size_t)E * sizeof(PackedEdge));
    const size_t csrB = sgB + degB + rowB + bsB + pkB;

    if (wtB + hallB + csrB <= ws_size) {
        // ------------------ full-graph CSR path ------------------
        bf16_t* wt = (bf16_t*)ws;
        bf16_t* hall = (bf16_t*)(ws + wtB);
        char* tail = ws + wtB + hallB;
        float* sg = (float*)tail;
        int* deg = (int*)(tail + sgB);
        int* rowptr = (int*)(tail + sgB + degB);
        int* bsum = (int*)(tail + sgB + degB + rowB);
        PackedEdge* packed = (PackedEdge*)(tail + sgB + degB + rowB + bsB);

        k_convert_w<<<(NRELS * FEAT * FEAT + 255) / 256, 256, 0, stream>>>(w, wt);
        k_gate<<<(N + 3) / 4, 256, 0, stream>>>(h, gw, sg, 0, N);
        k_gemm8<<<Nceil / GT, 256, 0, stream>>>(h, wt, sg, hall, N, Nceil * FEAT);
        hipMemsetAsync(deg, 0, (size_t)N * sizeof(int), stream);
        k_degree<<<(E + 255) / 256, 256, 0, stream>>>(dst, deg, E);
        k_scan_block<<<nb, 256, 0, stream>>>(deg, rowptr, bsum, N);
        k_scan_tops<<<1, 1024, 0, stream>>>(bsum, nb, rowptr + N);
        k_scan_add<<<(N + 255) / 256, 256, 0, stream>>>(rowptr, bsum, N);
        hipMemsetAsync(deg, 0, (size_t)N * sizeof(int), stream);          // reuse as cursor
        k_fill<<<(E + 255) / 256, 256, 0, stream>>>(src, dst, rel, nrm, rowptr, deg,
                                                    packed, Nceil, E);
        k_gather<<<(N + 3) / 4, 256, 0, stream>>>(hall, packed, rowptr, out, N);
    } else {
        // ------------------ chunked atomic fallback ------------------
        bf16_t* wt = (bf16_t*)ws;
        const size_t per_node = NRELS * sizeof(float)
                              + (size_t)NRELS * FEAT * sizeof(bf16_t);
        size_t avail = ws_size > wtB ? ws_size - wtB : 0;
        long long cmax = (long long)(avail / per_node);
        int C = (int)((cmax / GT) * GT);
        if (C > Nceil) C = Nceil;
        if (C < GT) C = GT;
        float* sg = (float*)(ws + wtB);
        bf16_t* hall = (bf16_t*)(ws + wtB + (size_t)C * NRELS * sizeof(float));

        hipMemsetAsync(d_out, 0, (size_t)N * FEAT * sizeof(float), stream);
        k_convert_w<<<(NRELS * FEAT * FEAT + 255) / 256, 256, 0, stream>>>(w, wt);
        for (int node0 = 0; node0 < N; node0 += C) {
            int nc = N - node0;
            if (nc > C) nc = C;
            int ncceil = ((nc + GT - 1) / GT) * GT;
            k_gate<<<(nc + 3) / 4, 256, 0, stream>>>(h, gw, sg, node0, nc);
            k_gemm8<<<ncceil / GT, 256, 0, stream>>>(h + (size_t)node0 * FEAT, wt, sg,
                                                     hall, nc, ncceil * FEAT);
            k_scatter<<<(E + 3) / 4, 256, 0, stream>>>(hall, nrm, src, dst, rel, out,
                                                       node0, nc, ncceil, E);
        }
        k_relu<<<((N * FEAT / 4) + 255) / 256, 256, 0, stream>>>((float4*)out, N * FEAT / 4);
    }
}

// Round 5
// 366.019 us; speedup vs baseline: 2.2165x; 1.4307x over previous
//
#include <hip/hip_runtime.h>
#include <hip/hip_bf16.h>

#define FEAT 128
#define NRELS 8
#define KTOT 1024          // NRELS * FEAT
#define BN 32              // dst nodes per aggemm block
#define SCAN2 1024

typedef __bf16 bf16_t;
typedef __bf16 bf16x4_t __attribute__((ext_vector_type(4)));
typedef __bf16 bf16x8_t __attribute__((ext_vector_type(8)));
typedef float f32x4 __attribute__((ext_vector_type(4)));

struct __align__(8) PackedEdge { int row; float scale; };  // row = (src<<3)|rel

static inline size_t align256(size_t x) { return (x + 255) & ~(size_t)255; }

// ---------------------------------------------------------------------------
// w [R][d][f] fp32 -> wt2 [f][r*128+d] bf16 : GEMM B-operand, k=(r,d)
// contiguous per f row. 256 KiB total, L2-resident during GEMM.
__global__ void k_convert_w2(const float* __restrict__ w, bf16_t* __restrict__ wt2) {
    int i = blockIdx.x * blockDim.x + threadIdx.x;
    if (i >= NRELS * FEAT * FEAT) return;
    int r = i >> 14;
    int rem = i & 16383;
    int d = rem >> 7;
    int f = rem & 127;
    wt2[(size_t)f * KTOT + r * FEAT + d] = (bf16_t)w[i];
}

// ---------------------------------------------------------------------------
// h fp32 -> hb bf16 [N][128]. 25.6 MB -> L3-resident for the edge gathers.
__global__ void k_convert_h(const float* __restrict__ h, bf16x4_t* __restrict__ hb4,
                            int ntotal) {
    int i = blockIdx.x * blockDim.x + threadIdx.x;
    if (i >= ntotal * (FEAT / 4)) return;
    float4 v = reinterpret_cast<const float4*>(h)[i];
    bf16x4_t o;
    o.x = (bf16_t)v.x; o.y = (bf16_t)v.y; o.z = (bf16_t)v.z; o.w = (bf16_t)v.w;
    hb4[i] = o;
}

// ---------------------------------------------------------------------------
// Gate: sg[n][r] = sigmoid(sum_d h[n][d]*gw[r][d]); fp32. One wave per node.
// Lane partition: lane = r*8 + g; each lane dots 16 d's of rel r; 3-step
// shfl_xor reduce within the 8-lane group (verified round 4).
__global__ __launch_bounds__(256) void k_gate(const float* __restrict__ h,
                                              const float* __restrict__ gw,
                                              float* __restrict__ sg, int ncount) {
    int wv = (int)((blockIdx.x * blockDim.x + threadIdx.x) >> 6);
    int lane = threadIdx.x & 63;
    if (wv >= ncount) return;
    int r = lane >> 3;          // relation 0..7
    int g = lane & 7;           // d-group: d in [g*16, g*16+16)
    const float4* hp = reinterpret_cast<const float4*>(h + (size_t)wv * FEAT + g * 16);
    const float4* wp = reinterpret_cast<const float4*>(gw + r * FEAT + g * 16);
    float s = 0.f;
#pragma unroll
    for (int i = 0; i < 4; ++i) {
        float4 a = hp[i];
        float4 b = wp[i];
        s += a.x * b.x + a.y * b.y + a.z * b.z + a.w * b.w;
    }
    s += __shfl_xor(s, 1, 64);
    s += __shfl_xor(s, 2, 64);
    s += __shfl_xor(s, 4, 64);
    if (g == 0) sg[(size_t)wv * NRELS + r] = 1.0f / (1.0f + __expf(-s));
}

// ---------------------------------------------------------------------------
// CSR build keyed by (dst, rel): 8*N segments -> per-node edge runs arrive
// rel-grouped, so each 16-lane aggregator keeps ONE live fp32 accumulator.
__global__ void k_degree8(const int* __restrict__ dstv, const int* __restrict__ rel,
                          int* __restrict__ deg8, int nedges) {
    int e = blockIdx.x * blockDim.x + threadIdx.x;
    if (e >= nedges) return;
    atomicAdd(&deg8[(dstv[e] << 3) | rel[e]], 1);
}

__global__ __launch_bounds__(1024) void k_scan_block2(const int* __restrict__ in,
                                                      int* __restrict__ outv,
                                                      int* __restrict__ bsum, int n) {
    __shared__ int sm[1024];
    int t = threadIdx.x;
    int idx = blockIdx.x * SCAN2 + t;
    int v = (idx < n) ? in[idx] : 0;
    sm[t] = v;
    __syncthreads();
    for (int off = 1; off < 1024; off <<= 1) {
        int x = (t >= off) ? sm[t - off] : 0;
        __syncthreads();
        sm[t] += x;
        __syncthreads();
    }
    if (idx < n) outv[idx] = sm[t] - v;
    if (t == 1023) bsum[blockIdx.x] = sm[1023];
}

__global__ __launch_bounds__(1024) void k_scan_tops(int* __restrict__ bsum, int nb,
                                                    int* __restrict__ rowptr_end) {
    __shared__ int sm[1024];
    int t = threadIdx.x;
    if (nb <= 1024) {
        int v = (t < nb) ? bsum[t] : 0;
        sm[t] = v;
        __syncthreads();
        for (int off = 1; off < 1024; off <<= 1) {
            int x = (t >= off) ? sm[t - off] : 0;
            __syncthreads();
            sm[t] += x;
            __syncthreads();
        }
        if (t < nb) bsum[t] = sm[t] - v;
        if (t == 1023) *rowptr_end = sm[1023];
    } else if (t == 0) {
        int run = 0;
        for (int b = 0; b < nb; ++b) { int v = bsum[b]; bsum[b] = run; run += v; }
        *rowptr_end = run;
    }
}

__global__ void k_scan_add2(int* __restrict__ rowptr, const int* __restrict__ bsum, int n) {
    int i = blockIdx.x * blockDim.x + threadIdx.x;
    if (i >= n) return;
    rowptr[i] += bsum[i >> 10];   // SCAN2 = 1<<10
}

// Fill packed records {(src<<3)|rel, norm*sigmoid_gate} at (dst,rel)-CSR slots.
__global__ void k_fill8(const int* __restrict__ src, const int* __restrict__ dstv,
                        const int* __restrict__ rel, const float* __restrict__ nrm,
                        const float* __restrict__ sg, const int* __restrict__ rp8,
                        int* __restrict__ cursor, PackedEdge* __restrict__ packed,
                        int nedges) {
    int e = blockIdx.x * blockDim.x + threadIdx.x;
    if (e >= nedges) return;
    int d = dstv[e];
    int s = src[e];
    int r = rel[e];
    int key = (d << 3) | r;
    int pos = rp8[key] + atomicAdd(&cursor[key], 1);
    PackedEdge p;
    p.row = (s << 3) | r;
    p.scale = nrm[e] * sg[(size_t)s * NRELS + r];
    packed[pos] = p;
}

// ---------------------------------------------------------------------------
// Fused aggregate + GEMM + relu. Block = 512 threads (8 waves), 32 dst nodes.
// LDS: agg bf16 [32 rows][2048 B], XOR-swizzled at 16B chunks (chunk^(node&7)).
// 64 KiB -> 2 blocks/CU.
//
// Phase A: one 16-lane GROUP per dst node (32 concurrent edge-chains/block, 4x
//   round-2's parallelism; exclusive node ownership -> NO atomics). Per edge:
//   16 lanes read the src's 256B hb row (bf16x8/lane), fp32-FMA into 8 regs;
//   edges arrive rel-grouped (CSR by (dst,rel)), so on rel change the group
//   flushes ONE swizzled bf16x8/lane to LDS. Single bf16 rounding per cell --
//   numerics identical to round 2 (harness-passed).
// Phase B (round-2 verbatim): M=32 x N=128 x K=1024 MFMA GEMM; A via swizzled
//   16B LDS reads, B bf16x8 from L2-hot wt2; C -> aliased LDS [32][132];
//   relu + fully-coalesced float4 stores.
__global__ __launch_bounds__(512, 2) void k_aggemm(const bf16_t* __restrict__ hb,
                                                   const bf16_t* __restrict__ wt2,
                                                   const PackedEdge* __restrict__ packed,
                                                   const int* __restrict__ rp8,
                                                   float* __restrict__ out, int nnodes) {
    __shared__ __align__(16) char lds_raw[BN * KTOT * sizeof(bf16_t)];   // 64 KiB
    float* cst = (float*)lds_raw;                 // aliased C-stage [32][132]
    const int t = threadIdx.x;
    const int nb0 = blockIdx.x * BN;

    // zero agg tile: 64 KiB / 512 threads = 8 x 16B each
    {
        f32x4 z = {0.f, 0.f, 0.f, 0.f};
#pragma unroll
        for (int i = 0; i < 8; ++i)
            reinterpret_cast<f32x4*>(lds_raw)[t + i * 512] = z;
    }
    __syncthreads();

    // ---------------- Phase A: per-node 16-lane aggregation ----------------
    {
        const int g = t >> 4;            // group = local node 0..31
        const int il = t & 15;           // 16B chunk lane within row
        const int sw = g & 7;
        const int gnode = nb0 + g;
        int beg = 0, end = 0;
        if (gnode < nnodes) {
            beg = rp8[gnode * 8];
            end = rp8[gnode * 8 + 8];
        }
        float a[8];
#pragma unroll
        for (int i = 0; i < 8; ++i) a[i] = 0.f;

        int j = beg;
        PackedEdge p0 = {0, 0.f}, p1 = {0, 0.f};
        bf16x8_t v0;
#pragma unroll
        for (int i = 0; i < 8; ++i) v0[i] = (bf16_t)0.f;
        if (j < end) {
            p0 = packed[j];
            v0 = *reinterpret_cast<const bf16x8_t*>(
                hb + ((size_t)(p0.row >> 3) << 7) + il * 8);
        }
        if (j + 1 < end) p1 = packed[j + 1];
        int cur_r = (j < end) ? (p0.row & 7) : -1;

#pragma unroll 1
        for (; j < end; ++j) {
            bf16x8_t v1 = v0;
            if (j + 1 < end)                       // prefetch next hb row
                v1 = *reinterpret_cast<const bf16x8_t*>(
                    hb + ((size_t)(p1.row >> 3) << 7) + il * 8);
            PackedEdge p2 = p1;
            if (j + 2 < end) p2 = packed[j + 2];   // prefetch next-next record
            int r = p0.row & 7;
            if (r != cur_r) {                      // group-uniform branch
                bf16x8_t o;
#pragma unroll
                for (int i = 0; i < 8; ++i) o[i] = (bf16_t)a[i];
                int chunk = (cur_r * 16 + il) ^ sw;
                *reinterpret_cast<bf16x8_t*>(lds_raw + (size_t)g * 2048 + chunk * 16) = o;
#pragma unroll
                for (int i = 0; i < 8; ++i) a[i] = 0.f;
                cur_r = r;
            }
            float s = p0.scale;
#pragma unroll
            for (int i = 0; i < 8; ++i) a[i] += (float)v0[i] * s;
            p0 = p1; p1 = p2; v0 = v1;
        }
        if (cur_r >= 0) {
            bf16x8_t o;
#pragma unroll
            for (int i = 0; i < 8; ++i) o[i] = (bf16_t)a[i];
            int chunk = (cur_r * 16 + il) ^ sw;
            *reinterpret_cast<bf16x8_t*>(lds_raw + (size_t)g * 2048 + chunk * 16) = o;
        }
    }
    __syncthreads();

    // ---------------- Phase B: GEMM (round-2 verbatim) ----------------
    const int lane = t & 63;
    const int wv = t >> 6;               // 0..7, f-slice of 16 feats
    const int l15 = lane & 15;
    const int lhi = lane >> 4;
    f32x4 acc0 = {0.f, 0.f, 0.f, 0.f};
    f32x4 acc1 = {0.f, 0.f, 0.f, 0.f};
    const bf16_t* bp = wt2 + (size_t)(wv * 16 + l15) * KTOT + lhi * 8;
    const char* a0p = lds_raw + (size_t)l15 * 2048;        // node rows 0..15
    const char* a1p = a0p + 16 * 2048;                     // node rows 16..31
    const int sw = l15 & 7;                                // (16+l15)&7 == l15&7
#pragma unroll 4
    for (int ks = 0; ks < 32; ++ks) {
        int coff = ((ks * 4 + lhi) ^ sw) << 4;
        bf16x8_t av0 = *reinterpret_cast<const bf16x8_t*>(a0p + coff);
        bf16x8_t av1 = *reinterpret_cast<const bf16x8_t*>(a1p + coff);
        bf16x8_t bv = *reinterpret_cast<const bf16x8_t*>(bp + ks * 32);
        acc0 = __builtin_amdgcn_mfma_f32_16x16x32_bf16(av0, bv, acc0, 0, 0, 0);
        acc1 = __builtin_amdgcn_mfma_f32_16x16x32_bf16(av1, bv, acc1, 0, 0, 0);
    }
    __syncthreads();   // all agg reads done; safe to overwrite with C

    // C layout: col(l15)=f within wave slice, row(lhi*4+i)=node (m89-verified)
    {
        int f = wv * 16 + l15;
#pragma unroll
        for (int i = 0; i < 4; ++i) {
            int n0 = lhi * 4 + i;
            cst[n0 * 132 + f] = acc0[i];
            cst[(n0 + 16) * 132 + f] = acc1[i];
        }
    }
    __syncthreads();

    // relu + coalesced store: thread t -> node t>>4, feats (t&15)*8..+8
    {
        int node = t >> 4;
        int f0 = (t & 15) * 8;
        int gnode = nb0 + node;
        if (gnode < nnodes) {
            const float* cr = cst + node * 132 + f0;
            float4 o0, o1;
            o0.x = fmaxf(cr[0], 0.f); o0.y = fmaxf(cr[1], 0.f);
            o0.z = fmaxf(cr[2], 0.f); o0.w = fmaxf(cr[3], 0.f);
            o1.x = fmaxf(cr[4], 0.f); o1.y = fmaxf(cr[5], 0.f);
            o1.z = fmaxf(cr[6], 0.f); o1.w = fmaxf(cr[7], 0.f);
            float4* op = reinterpret_cast<float4*>(out + (size_t)gnode * FEAT + f0);
            op[0] = o0;
            op[1] = o1;
        }
    }
}

// ---------------------------------------------------------------------------
extern "C" void kernel_launch(void* const* d_in, const int* in_sizes, int n_in,
                              void* d_out, int out_size, void* d_ws, size_t ws_size,
                              hipStream_t stream) {
    const float* h = (const float*)d_in[0];
    const float* w = (const float*)d_in[1];
    const float* gw = (const float*)d_in[2];
    const float* nrm = (const float*)d_in[3];
    const int* src = (const int*)d_in[4];
    const int* dst = (const int*)d_in[5];
    const int* rel = (const int*)d_in[6];
    float* out = (float*)d_out;

    const int N = in_sizes[0] / FEAT;
    const int E = in_sizes[4];
    const int NSEG = N * NRELS;                       // 800K (dst,rel) segments
    const int nb2 = (NSEG + SCAN2 - 1) / SCAN2;
    const int nbk = (N + BN - 1) / BN;

    char* ws = (char*)d_ws;
    const size_t wt2B = align256((size_t)FEAT * KTOT * sizeof(bf16_t));   // 256 KiB
    const size_t hbB  = align256((size_t)N * FEAT * sizeof(bf16_t));      // 25.6 MB
    const size_t sgB  = align256((size_t)N * NRELS * sizeof(float));      // 3.2 MB
    const size_t dgB  = align256((size_t)NSEG * sizeof(int));             // 3.2 MB
    const size_t rpB  = align256((size_t)(NSEG + 1) * sizeof(int));       // 3.2 MB
    const size_t bsB  = align256((size_t)nb2 * sizeof(int));

    bf16_t* wt2 = (bf16_t*)ws;
    bf16_t* hb = (bf16_t*)(ws + wt2B);
    float* sg = (float*)(ws + wt2B + hbB);
    int* deg8 = (int*)(ws + wt2B + hbB + sgB);        // reused as cursor after scan
    int* rp8 = (int*)(ws + wt2B + hbB + sgB + dgB);
    int* bsum = (int*)(ws + wt2B + hbB + sgB + dgB + rpB);
    PackedEdge* packed = (PackedEdge*)(ws + wt2B + hbB + sgB + dgB + rpB + bsB);

    k_convert_w2<<<(NRELS * FEAT * FEAT + 255) / 256, 256, 0, stream>>>(w, wt2);
    k_convert_h<<<(N * (FEAT / 4) + 255) / 256, 256, 0, stream>>>(h, (bf16x4_t*)hb, N);
    k_gate<<<(N + 3) / 4, 256, 0, stream>>>(h, gw, sg, N);

    hipMemsetAsync(deg8, 0, (size_t)NSEG * sizeof(int), stream);
    k_degree8<<<(E + 255) / 256, 256, 0, stream>>>(dst, rel, deg8, E);
    k_scan_block2<<<nb2, 1024, 0, stream>>>(deg8, rp8, bsum, NSEG);
    k_scan_tops<<<1, 1024, 0, stream>>>(bsum, nb2, rp8 + NSEG);
    k_scan_add2<<<(NSEG + 255) / 256, 256, 0, stream>>>(rp8, bsum, NSEG);
    hipMemsetAsync(deg8, 0, (size_t)NSEG * sizeof(int), stream);   // cursor
    k_fill8<<<(E + 255) / 256, 256, 0, stream>>>(src, dst, rel, nrm, sg, rp8, deg8,
                                                 packed, E);

    k_aggemm<<<nbk, 512, 0, stream>>>(hb, wt2, packed, rp8, out, N);
}

// Round 6
// 346.585 us; speedup vs baseline: 2.3407x; 1.0561x over previous
//
#include <hip/hip_runtime.h>
#include <hip/hip_bf16.h>

#define FEAT 128
#define NRELS 8
#define KTOT 1024          // NRELS * FEAT
#define BN 32              // dst nodes per aggemm block
#define SCAN2 1024

typedef __bf16 bf16_t;
typedef __bf16 bf16x2_t __attribute__((ext_vector_type(2)));
typedef __bf16 bf16x4_t __attribute__((ext_vector_type(4)));
typedef __bf16 bf16x8_t __attribute__((ext_vector_type(8)));
typedef float f32x4 __attribute__((ext_vector_type(4)));

struct __align__(8) PackedEdge { int row; float scale; };  // row = (src<<3)|rel

static inline size_t align256(size_t x) { return (x + 255) & ~(size_t)255; }

// ---------------------------------------------------------------------------
// w [R][d][f] fp32 -> wt2 [f][r*128+d] bf16 : GEMM B-operand, k=(r,d)
// contiguous per f row. 256 KiB total, L2-resident during GEMM.
__global__ void k_convert_w2(const float* __restrict__ w, bf16_t* __restrict__ wt2) {
    int i = blockIdx.x * blockDim.x + threadIdx.x;
    if (i >= NRELS * FEAT * FEAT) return;
    int r = i >> 14;
    int rem = i & 16383;
    int d = rem >> 7;
    int f = rem & 127;
    wt2[(size_t)f * KTOT + r * FEAT + d] = (bf16_t)w[i];
}

// ---------------------------------------------------------------------------
// Fused h->hb convert + gate. One wave per node; h row is read once (the
// second access pattern hits L1). Gate lane partition (verified round 4):
// lane = r*8+g, 16 d's per lane, 3-step shfl_xor reduce.
__global__ __launch_bounds__(256) void k_prep(const float* __restrict__ h,
                                              const float* __restrict__ gw,
                                              float* __restrict__ sg,
                                              bf16_t* __restrict__ hb, int ncount) {
    int wv = (int)((blockIdx.x * blockDim.x + threadIdx.x) >> 6);
    int lane = threadIdx.x & 63;
    if (wv >= ncount) return;

    // convert: lane covers 2 floats -> bf16x2 (256B/wave, coalesced)
    float2 hv2 = *reinterpret_cast<const float2*>(h + (size_t)wv * FEAT + lane * 2);
    bf16x2_t hc;
    hc.x = (bf16_t)hv2.x;
    hc.y = (bf16_t)hv2.y;
    *reinterpret_cast<bf16x2_t*>(hb + (size_t)wv * FEAT + lane * 2) = hc;

    // gate
    int r = lane >> 3;          // relation 0..7
    int g = lane & 7;           // d-group: d in [g*16, g*16+16)
    const float4* hp = reinterpret_cast<const float4*>(h + (size_t)wv * FEAT + g * 16);
    const float4* wp = reinterpret_cast<const float4*>(gw + r * FEAT + g * 16);
    float s = 0.f;
#pragma unroll
    for (int i = 0; i < 4; ++i) {
        float4 a = hp[i];
        float4 b = wp[i];
        s += a.x * b.x + a.y * b.y + a.z * b.z + a.w * b.w;
    }
    s += __shfl_xor(s, 1, 64);
    s += __shfl_xor(s, 2, 64);
    s += __shfl_xor(s, 4, 64);
    if (g == 0) sg[(size_t)wv * NRELS + r] = 1.0f / (1.0f + __expf(-s));
}

// ---------------------------------------------------------------------------
// CSR build keyed by (dst, rel): 8*N segments -> per-node edge runs arrive
// rel-grouped, so each 16-lane aggregator keeps ONE live fp32 accumulator.
__global__ void k_degree8(const int* __restrict__ dstv, const int* __restrict__ rel,
                          int* __restrict__ deg8, int nedges) {
    int e = blockIdx.x * blockDim.x + threadIdx.x;
    if (e >= nedges) return;
    atomicAdd(&deg8[(dstv[e] << 3) | rel[e]], 1);
}

__global__ __launch_bounds__(1024) void k_scan_block2(const int* __restrict__ in,
                                                      int* __restrict__ outv,
                                                      int* __restrict__ bsum, int n) {
    __shared__ int sm[1024];
    int t = threadIdx.x;
    int idx = blockIdx.x * SCAN2 + t;
    int v = (idx < n) ? in[idx] : 0;
    sm[t] = v;
    __syncthreads();
    for (int off = 1; off < 1024; off <<= 1) {
        int x = (t >= off) ? sm[t - off] : 0;
        __syncthreads();
        sm[t] += x;
        __syncthreads();
    }
    if (idx < n) outv[idx] = sm[t] - v;
    if (t == 1023) bsum[blockIdx.x] = sm[1023];
}

__global__ __launch_bounds__(1024) void k_scan_tops(int* __restrict__ bsum, int nb,
                                                    int* __restrict__ rowptr_end) {
    __shared__ int sm[1024];
    int t = threadIdx.x;
    if (nb <= 1024) {
        int v = (t < nb) ? bsum[t] : 0;
        sm[t] = v;
        __syncthreads();
        for (int off = 1; off < 1024; off <<= 1) {
            int x = (t >= off) ? sm[t - off] : 0;
            __syncthreads();
            sm[t] += x;
            __syncthreads();
        }
        if (t < nb) bsum[t] = sm[t] - v;
        if (t == 1023) *rowptr_end = sm[1023];
    } else if (t == 0) {
        int run = 0;
        for (int b = 0; b < nb; ++b) { int v = bsum[b]; bsum[b] = run; run += v; }
        *rowptr_end = run;
    }
}

// Adds block offsets AND writes the working cursor copy (saves a memset and
// the rp8 read in k_fill8).
__global__ void k_scan_add2(int* __restrict__ rowptr, const int* __restrict__ bsum,
                            int* __restrict__ wcur, int n) {
    int i = blockIdx.x * blockDim.x + threadIdx.x;
    if (i >= n) return;
    int v = rowptr[i] + bsum[i >> 10];   // SCAN2 = 1<<10
    rowptr[i] = v;
    wcur[i] = v;
}

// Fill packed records {(src<<3)|rel, norm*sigmoid_gate} at (dst,rel)-CSR slots.
// wcur holds the running cursor (pre-seeded with rp8 values).
__global__ void k_fill8(const int* __restrict__ src, const int* __restrict__ dstv,
                        const int* __restrict__ rel, const float* __restrict__ nrm,
                        const float* __restrict__ sg, int* __restrict__ wcur,
                        PackedEdge* __restrict__ packed, int nedges) {
    int e = blockIdx.x * blockDim.x + threadIdx.x;
    if (e >= nedges) return;
    int d = dstv[e];
    int s = src[e];
    int r = rel[e];
    int pos = atomicAdd(&wcur[(d << 3) | r], 1);
    PackedEdge p;
    p.row = (s << 3) | r;
    p.scale = nrm[e] * sg[(size_t)s * NRELS + r];
    packed[pos] = p;
}

// ---------------------------------------------------------------------------
// Fused aggregate + GEMM + relu. Block = 512 threads (8 waves), 32 dst nodes.
// LDS: agg bf16 [32 rows][2048 B], XOR-swizzled at 16B chunks (chunk^(node&7)).
// 64 KiB -> 2 blocks/CU; launch_bounds(512,4) caps VGPR at 128 so the LDS
// limit (not registers) decides occupancy.
//
// Phase A: one 16-lane GROUP per dst node, depth-4 software pipeline:
//   4 hb-row loads in flight (batched), packed records 2 super-iters ahead
//   (p/q/r rings, statically indexed). Edge consumption order per group is
//   identical to round 5 -> bitwise-same numerics. Flush on rel change
//   (group-uniform; CSR is (dst,rel)-sorted).
// Phase B (verified): M=32 x N=128 x K=1024 MFMA GEMM; A via swizzled 16B
//   LDS reads, B bf16x8 from L2-hot wt2; C -> aliased LDS [32][132];
//   relu + fully-coalesced float4 stores.
__global__ __launch_bounds__(512, 4) void k_aggemm(const bf16_t* __restrict__ hb,
                                                   const bf16_t* __restrict__ wt2,
                                                   const PackedEdge* __restrict__ packed,
                                                   const int* __restrict__ rp8,
                                                   float* __restrict__ out, int nnodes) {
    __shared__ __align__(16) char lds_raw[BN * KTOT * sizeof(bf16_t)];   // 64 KiB
    float* cst = (float*)lds_raw;                 // aliased C-stage [32][132]
    const int t = threadIdx.x;
    const int nb0 = blockIdx.x * BN;

    // zero agg tile: 64 KiB / 512 threads = 8 x 16B each
    {
        f32x4 z = {0.f, 0.f, 0.f, 0.f};
#pragma unroll
        for (int i = 0; i < 8; ++i)
            reinterpret_cast<f32x4*>(lds_raw)[t + i * 512] = z;
    }
    __syncthreads();

    // ---------------- Phase A: depth-4 pipelined aggregation ----------------
    {
        const int g = t >> 4;            // group = local node 0..31
        const int il = t & 15;           // 16B chunk lane within row
        const int sw = g & 7;
        const int gnode = nb0 + g;
        int beg = 0, end = 0;
        if (gnode < nnodes) {
            beg = rp8[gnode * 8];
            end = rp8[gnode * 8 + 8];
        }

        if (beg < end) {
            float a[8];
#pragma unroll
            for (int i = 0; i < 8; ++i) a[i] = 0.f;
            int cur_r;

            auto ldrow = [&](const PackedEdge& p) {
                return *reinterpret_cast<const bf16x8_t*>(
                    hb + ((size_t)(p.row >> 3) << 7) + il * 8);
            };
            auto flush = [&](int rr) {
                bf16x8_t o;
#pragma unroll
                for (int i = 0; i < 8; ++i) o[i] = (bf16_t)a[i];
                int chunk = (rr * 16 + il) ^ sw;
                *reinterpret_cast<bf16x8_t*>(lds_raw + (size_t)g * 2048 + chunk * 16) = o;
            };
            auto consume = [&](const PackedEdge& p, const bf16x8_t& v, int idx) {
                if (idx < end) {
                    int r = p.row & 7;
                    if (r != cur_r) {            // group-uniform branch
                        flush(cur_r);
#pragma unroll
                        for (int i = 0; i < 8; ++i) a[i] = 0.f;
                        cur_r = r;
                    }
                    float s = p.scale;
#pragma unroll
                    for (int i = 0; i < 8; ++i) a[i] += (float)v[i] * s;
                }
            };

            int j = beg;
            PackedEdge p0, p1, p2, p3, q0, q1, q2, q3;
            p0 = packed[j];
            p1 = (j + 1 < end) ? packed[j + 1] : p0;
            p2 = (j + 2 < end) ? packed[j + 2] : p0;
            p3 = (j + 3 < end) ? packed[j + 3] : p0;
            q0 = (j + 4 < end) ? packed[j + 4] : p0;
            q1 = (j + 5 < end) ? packed[j + 5] : p0;
            q2 = (j + 6 < end) ? packed[j + 6] : p0;
            q3 = (j + 7 < end) ? packed[j + 7] : p0;
            bf16x8_t v0 = ldrow(p0);
            bf16x8_t v1 = ldrow(p1);
            bf16x8_t v2 = ldrow(p2);
            bf16x8_t v3 = ldrow(p3);
            cur_r = p0.row & 7;

#pragma unroll 1
            for (; j < end; j += 4) {
                // packed ring: load 2 super-iterations ahead
                PackedEdge r0 = p0, r1 = p0, r2 = p0, r3 = p0;
                if (j + 8 < end)  r0 = packed[j + 8];
                if (j + 9 < end)  r1 = packed[j + 9];
                if (j + 10 < end) r2 = packed[j + 10];
                if (j + 11 < end) r3 = packed[j + 11];

                consume(p0, v0, j);
                consume(p1, v1, j + 1);
                consume(p2, v2, j + 2);
                consume(p3, v3, j + 3);

                // issue next 4 row loads (q's packed loads completed last iter)
                v0 = ldrow(q0); v1 = ldrow(q1); v2 = ldrow(q2); v3 = ldrow(q3);
                p0 = q0; p1 = q1; p2 = q2; p3 = q3;
                q0 = r0; q1 = r1; q2 = r2; q3 = r3;
            }
            flush(cur_r);
        }
    }
    __syncthreads();

    // ---------------- Phase B: GEMM (round-5 verbatim) ----------------
    const int lane = t & 63;
    const int wv = t >> 6;               // 0..7, f-slice of 16 feats
    const int l15 = lane & 15;
    const int lhi = lane >> 4;
    f32x4 acc0 = {0.f, 0.f, 0.f, 0.f};
    f32x4 acc1 = {0.f, 0.f, 0.f, 0.f};
    const bf16_t* bp = wt2 + (size_t)(wv * 16 + l15) * KTOT + lhi * 8;
    const char* a0p = lds_raw + (size_t)l15 * 2048;        // node rows 0..15
    const char* a1p = a0p + 16 * 2048;                     // node rows 16..31
    const int sw = l15 & 7;                                // (16+l15)&7 == l15&7
#pragma unroll 4
    for (int ks = 0; ks < 32; ++ks) {
        int coff = ((ks * 4 + lhi) ^ sw) << 4;
        bf16x8_t av0 = *reinterpret_cast<const bf16x8_t*>(a0p + coff);
        bf16x8_t av1 = *reinterpret_cast<const bf16x8_t*>(a1p + coff);
        bf16x8_t bv = *reinterpret_cast<const bf16x8_t*>(bp + ks * 32);
        acc0 = __builtin_amdgcn_mfma_f32_16x16x32_bf16(av0, bv, acc0, 0, 0, 0);
        acc1 = __builtin_amdgcn_mfma_f32_16x16x32_bf16(av1, bv, acc1, 0, 0, 0);
    }
    __syncthreads();   // all agg reads done; safe to overwrite with C

    // C layout: col(l15)=f within wave slice, row(lhi*4+i)=node (m89-verified)
    {
        int f = wv * 16 + l15;
#pragma unroll
        for (int i = 0; i < 4; ++i) {
            int n0 = lhi * 4 + i;
            cst[n0 * 132 + f] = acc0[i];
            cst[(n0 + 16) * 132 + f] = acc1[i];
        }
    }
    __syncthreads();

    // relu + coalesced store: thread t -> node t>>4, feats (t&15)*8..+8
    {
        int node = t >> 4;
        int f0 = (t & 15) * 8;
        int gnode = nb0 + node;
        if (gnode < nnodes) {
            const float* cr = cst + node * 132 + f0;
            float4 o0, o1;
            o0.x = fmaxf(cr[0], 0.f); o0.y = fmaxf(cr[1], 0.f);
            o0.z = fmaxf(cr[2], 0.f); o0.w = fmaxf(cr[3], 0.f);
            o1.x = fmaxf(cr[4], 0.f); o1.y = fmaxf(cr[5], 0.f);
            o1.z = fmaxf(cr[6], 0.f); o1.w = fmaxf(cr[7], 0.f);
            float4* op = reinterpret_cast<float4*>(out + (size_t)gnode * FEAT + f0);
            op[0] = o0;
            op[1] = o1;
        }
    }
}

// ---------------------------------------------------------------------------
extern "C" void kernel_launch(void* const* d_in, const int* in_sizes, int n_in,
                              void* d_out, int out_size, void* d_ws, size_t ws_size,
                              hipStream_t stream) {
    const float* h = (const float*)d_in[0];
    const float* w = (const float*)d_in[1];
    const float* gw = (const float*)d_in[2];
    const float* nrm = (const float*)d_in[3];
    const int* src = (const int*)d_in[4];
    const int* dst = (const int*)d_in[5];
    const int* rel = (const int*)d_in[6];
    float* out = (float*)d_out;

    const int N = in_sizes[0] / FEAT;
    const int E = in_sizes[4];
    const int NSEG = N * NRELS;                       // 800K (dst,rel) segments
    const int nb2 = (NSEG + SCAN2 - 1) / SCAN2;
    const int nbk = (N + BN - 1) / BN;

    char* ws = (char*)d_ws;
    const size_t wt2B = align256((size_t)FEAT * KTOT * sizeof(bf16_t));   // 256 KiB
    const size_t hbB  = align256((size_t)N * FEAT * sizeof(bf16_t));      // 25.6 MB
    const size_t sgB  = align256((size_t)N * NRELS * sizeof(float));      // 3.2 MB
    const size_t dgB  = align256((size_t)NSEG * sizeof(int));             // 3.2 MB
    const size_t rpB  = align256((size_t)(NSEG + 1) * sizeof(int));       // 3.2 MB
    const size_t bsB  = align256((size_t)nb2 * sizeof(int));

    bf16_t* wt2 = (bf16_t*)ws;
    bf16_t* hb = (bf16_t*)(ws + wt2B);
    float* sg = (float*)(ws + wt2B + hbB);
    int* deg8 = (int*)(ws + wt2B + hbB + sgB);        // scan input, then cursor
    int* rp8 = (int*)(ws + wt2B + hbB + sgB + dgB);
    int* bsum = (int*)(ws + wt2B + hbB + sgB + dgB + rpB);
    PackedEdge* packed = (PackedEdge*)(ws + wt2B + hbB + sgB + dgB + rpB + bsB);

    k_convert_w2<<<(NRELS * FEAT * FEAT + 255) / 256, 256, 0, stream>>>(w, wt2);
    k_prep<<<(N + 3) / 4, 256, 0, stream>>>(h, gw, sg, hb, N);

    hipMemsetAsync(deg8, 0, (size_t)NSEG * sizeof(int), stream);
    k_degree8<<<(E + 255) / 256, 256, 0, stream>>>(dst, rel, deg8, E);
    k_scan_block2<<<nb2, 1024, 0, stream>>>(deg8, rp8, bsum, NSEG);
    k_scan_tops<<<1, 1024, 0, stream>>>(bsum, nb2, rp8 + NSEG);
    k_scan_add2<<<(NSEG + 255) / 256, 256, 0, stream>>>(rp8, bsum, deg8, NSEG);
    k_fill8<<<(E + 255) / 256, 256, 0, stream>>>(src, dst, rel, nrm, sg, deg8,
                                                 packed, E);

    k_aggemm<<<nbk, 512, 0, stream>>>(hb, wt2, packed, rp8, out, N);
}